// Round 3
// baseline (1270.583 us; speedup 1.0000x reference)
//
#include <hip/hip_runtime.h>
#include <math.h>
#include <stdint.h>

typedef _Float16 f16;
typedef _Float16 f16x8 __attribute__((ext_vector_type(8)));
typedef float f32x4 __attribute__((ext_vector_type(4)));
typedef unsigned short u16;
typedef u16 u16x8 __attribute__((ext_vector_type(8)));

#define HID 256
#define K1ACT 3202
#define NS1 101               // ceil(3202/32), padded K = 3232
#define NS2 8                 // 256/32
#define NPX 65536
#define BPX 128               // pixels per block
#define NBLK (NPX/BPX)        // 512

// ws layout (bytes)
#define OFF_W1 0
#define SZ_W1  ((size_t)NS1*32768)
#define OFF_W2 SZ_W1
#define SZ_W2  ((size_t)NS2*32768)
#define OFF_W3 (OFF_W2+SZ_W2)
#define OFF_H  ((size_t)4194304)

__device__ inline void split2(float v, u16& h, u16& l){
  f16 hv = (f16)v;
  f16 lv = (f16)(v - (float)hv);
  h = __builtin_bit_cast(u16, hv);
  l = __builtin_bit_cast(u16, lv);
}

// Pre-split W (fp32 [K][256]) into fp16 hi/lo MFMA-fragment units (as round 2):
//   unit(s, w, nf, split, lane): 8 f16, j -> W[s*32 + (lane>>4)*8 + j][w*64 + nf*16 + (lane&15)]
//   unit offset = (((s*4 + w)*4 + nf)*2 + split)*64 + lane
__global__ void prep_w(const float* __restrict__ W, int Kact, int nStages,
                       u16* __restrict__ outp){
  int t = blockIdx.x*256 + threadIdx.x;
  if (t >= nStages*1024) return;
  int s = t >> 10, r = t & 1023;
  int w = r >> 8, nf = (r >> 6) & 3, l = r & 63;
  int col = w*64 + nf*16 + (l & 15);
  int kb  = s*32 + (l >> 4)*8;
  u16x8 hv, lv;
  #pragma unroll
  for (int j = 0; j < 8; ++j){
    int k = kb + j;
    float v = (k < Kact) ? W[(size_t)k*HID + col] : 0.f;
    u16 h, lo; split2(v, h, lo);
    hv[j] = h; lv[j] = lo;
  }
  size_t U0 = ((((size_t)s*4 + w)*4 + nf)*2 + 0)*64 + l;
  *(u16x8*)(outp + U0*8)      = hv;
  *(u16x8*)(outp + (U0+64)*8) = lv;
}

// ---------------------------------------------------------------------------
// 2-phase double-buffered fused GEMM layer.
// Block: 128 px x 256 cols, 512 threads = 8 waves (wm = wv>>2 px-half, wn = wv&3 col-64).
// MODE 0: A = im2col(xi)+coords; MODE 1: A = h; MODE 2: A = h, fused layer-4 tail.
// ---------------------------------------------------------------------------
template<int MODE>
__global__ __launch_bounds__(512, 2)
void gemm_layer(const float* __restrict__ xi, const uint32_t* __restrict__ hin,
                const u16* __restrict__ Wp, const float* __restrict__ bias,
                uint32_t* __restrict__ hout, const float* __restrict__ W4,
                const float* __restrict__ b4, float* __restrict__ out, int nt)
{
  __shared__ __align__(16) u16 Ab[2][8192];    // 16 KB each: (mfb*2+split)*64+l units
  __shared__ __align__(16) u16 Bb[2][16384];   // 32 KB each: ((wn*4+nf)*2+split)*64+l units
  __shared__ float red[8][BPX][3];             // MODE 2 partials (12 KB)

  const int tid  = threadIdx.x;
  const int lane = tid & 63;
  const int wv   = tid >> 6;
  const int wm   = wv >> 2, wn = wv & 3;

  int bid = blockIdx.x;
  bid = (bid & 7) * (NBLK/8) + (bid >> 3);     // XCD-chunked swizzle (bijective: 512%8==0)
  const int pxb = bid * BPX;
  const int y   = pxb >> 8;
  const int x0  = pxb & 255;

  // A-staging mapping: thread -> px, k-quarter
  const int pxl = ((tid >> 6) << 4) + (tid & 15);   // [0,128)
  const int kq  = (tid >> 4) & 3;                   // frag k-group

  const float gy  = -1.f + (2.f/255.f)*(float)y;
  const float gxA = -1.f + (2.f/255.f)*(float)(x0 + pxl);

  float    fa[8];
  uint32_t ua[8];

  auto A_LOAD = [&](int s){
    if (MODE == 0){
      #pragma unroll
      for (int j=0;j<8;++j){
        int k = s*32 + kq*8 + j;
        float v = 0.f;
        if (k < 3200){
          int c = k/25, rr = k - 25*c;
          int dy = rr/5, dx = rr - dy*5;
          int yy = y + dy - 2;
          int xx = x0 + pxl + dx - 2;
          if ((unsigned)yy < 256u && (unsigned)xx < 256u)
            v = xi[((size_t)c<<16) + ((size_t)yy<<8) + xx];
        } else if (k == 3200) v = gy;
        else if (k == 3201) v = gxA;
        fa[j] = v;
      }
    } else {
      const uint32_t* hp = hin + (size_t)(pxb + pxl)*HID + s*32 + kq*8;
      uint4 a0 = *(const uint4*)hp;
      uint4 a1 = *(const uint4*)(hp+4);
      ua[0]=a0.x; ua[1]=a0.y; ua[2]=a0.z; ua[3]=a0.w;
      ua[4]=a1.x; ua[5]=a1.y; ua[6]=a1.z; ua[7]=a1.w;
    }
  };

  auto A_WRITE = [&](int buf){
    u16x8 hv, lv;
    if (MODE == 0){
      #pragma unroll
      for (int j=0;j<8;++j){ u16 h,l; split2(fa[j],h,l); hv[j]=h; lv[j]=l; }
    } else {
      #pragma unroll
      for (int j=0;j<8;++j){ hv[j]=(u16)(ua[j]&0xffffu); lv[j]=(u16)(ua[j]>>16); }
    }
    const int mfb = tid >> 6;
    const int lsl = kq*16 + (tid & 15);
    *(u16x8*)(&Ab[buf][((size_t)(mfb*2+0)*64 + lsl)*8]) = hv;
    *(u16x8*)(&Ab[buf][((size_t)(mfb*2+1)*64 + lsl)*8]) = lv;
  };

  auto B_STAGE = [&](int s, int buf){
    const char* src = (const char*)Wp + (size_t)s*32768 + (size_t)wv*1024 + (size_t)lane*16;
    #pragma unroll
    for (int i=0;i<4;++i){
      __builtin_amdgcn_global_load_lds(
          (const __attribute__((address_space(1))) uint32_t*)(src + i*8192),
          (__attribute__((address_space(3))) uint32_t*)(&Bb[buf][(size_t)wv*512 + i*4096]),
          16, 0, 0);
    }
  };

  f32x4 acc[4][4];
  #pragma unroll
  for (int a=0;a<4;a++)
    #pragma unroll
    for (int b=0;b<4;b++) acc[a][b] = f32x4{0.f,0.f,0.f,0.f};

  // prologue
  A_LOAD(0);
  B_STAGE(0, 0);
  A_WRITE(0);
  __syncthreads();

  int cur = 0;
  for (int t = 0; t < nt; ++t){
    const int nxt = cur ^ 1;
    if (t+1 < nt){
      A_LOAD(t+1);          // global -> regs, latency hides under MFMA
      B_STAGE(t+1, nxt);    // global -> LDS (vmcnt), lands before next barrier
    }
    // compute step t from buf[cur]
    f16x8 ah[4], al[4];
    #pragma unroll
    for (int mf=0;mf<4;++mf){
      const int mfb = wm*4 + mf;
      ah[mf] = *(const f16x8*)(&Ab[cur][((size_t)(mfb*2+0)*64 + lane)*8]);
      al[mf] = *(const f16x8*)(&Ab[cur][((size_t)(mfb*2+1)*64 + lane)*8]);
    }
    #pragma unroll
    for (int nf=0;nf<4;++nf){
      f16x8 bh = *(const f16x8*)(&Bb[cur][((size_t)((wn*4+nf)*2+0)*64 + lane)*8]);
      f16x8 bl = *(const f16x8*)(&Bb[cur][((size_t)((wn*4+nf)*2+1)*64 + lane)*8]);
      #pragma unroll
      for (int mf=0;mf<4;++mf){
        acc[mf][nf] = __builtin_amdgcn_mfma_f32_16x16x32_f16(ah[mf], bh, acc[mf][nf], 0,0,0);
        acc[mf][nf] = __builtin_amdgcn_mfma_f32_16x16x32_f16(al[mf], bh, acc[mf][nf], 0,0,0);
        acc[mf][nf] = __builtin_amdgcn_mfma_f32_16x16x32_f16(ah[mf], bl, acc[mf][nf], 0,0,0);
      }
    }
    if (t+1 < nt) A_WRITE(nxt);   // split + ds_write prefetched A into other buffer
    __syncthreads();              // drains vmcnt(0)+lgkmcnt(0); buffers flip
    cur = nxt;
  }

  float bcol[4];
  #pragma unroll
  for (int nf=0;nf<4;++nf) bcol[nf] = bias[wn*64 + nf*16 + (lane&15)];

  if (MODE != 2){
    #pragma unroll
    for (int mf=0;mf<4;++mf)
      #pragma unroll
      for (int nf=0;nf<4;++nf)
        #pragma unroll
        for (int j=0;j<4;++j){
          float z = acc[mf][nf][j] + bcol[nf];
          float h = sinf(30.f*z);
          u16 hh,ll; split2(h,hh,ll);
          int row = wm*64 + mf*16 + (lane>>4)*4 + j;
          int col = wn*64 + nf*16 + (lane&15);
          hout[(size_t)(pxb+row)*HID + col] = (uint32_t)hh | ((uint32_t)ll<<16);
        }
  } else {
    float w4v[4][3];
    #pragma unroll
    for (int nf=0;nf<4;++nf){
      int col = wn*64 + nf*16 + (lane&15);
      w4v[nf][0]=W4[col*3+0]; w4v[nf][1]=W4[col*3+1]; w4v[nf][2]=W4[col*3+2];
    }
    #pragma unroll
    for (int mf=0;mf<4;++mf)
      #pragma unroll
      for (int j=0;j<4;++j){
        float s0=0.f,s1=0.f,s2=0.f;
        #pragma unroll
        for (int nf=0;nf<4;++nf){
          float h = sinf(30.f*(acc[mf][nf][j] + bcol[nf]));
          s0 += h*w4v[nf][0]; s1 += h*w4v[nf][1]; s2 += h*w4v[nf][2];
        }
        #pragma unroll
        for (int m=1;m<16;m<<=1){
          s0 += __shfl_xor(s0, m);
          s1 += __shfl_xor(s1, m);
          s2 += __shfl_xor(s2, m);
        }
        if ((lane & 15) == 0){
          int row = wm*64 + mf*16 + (lane>>4)*4 + j;
          red[wv][row][0]=s0; red[wv][row][1]=s1; red[wv][row][2]=s2;
        }
      }
    __syncthreads();
    if (tid < 384){
      int px = tid & 127, c = tid >> 7;
      int wb = (px >> 6)*4;
      float v = red[wb+0][px][c]+red[wb+1][px][c]+red[wb+2][px][c]+red[wb+3][px][c] + b4[c];
      out[(size_t)c*NPX + pxb + px] = v;
    }
  }
}

// ---------------------------------------------------------------------------
extern "C" void kernel_launch(void* const* d_in, const int* in_sizes, int n_in,
                              void* d_out, int out_size, void* d_ws, size_t ws_size,
                              hipStream_t stream) {
  const float* xi = (const float*)d_in[0];
  const float* W1 = (const float*)d_in[1];
  const float* b1 = (const float*)d_in[2];
  const float* W2 = (const float*)d_in[3];
  const float* b2 = (const float*)d_in[4];
  const float* W3 = (const float*)d_in[5];
  const float* b3 = (const float*)d_in[6];
  const float* W4 = (const float*)d_in[7];
  const float* b4 = (const float*)d_in[8];
  float* out = (float*)d_out;

  char* ws = (char*)d_ws;
  u16* W1p = (u16*)(ws + OFF_W1);
  u16* W2p = (u16*)(ws + OFF_W2);
  u16* W3p = (u16*)(ws + OFF_W3);
  uint32_t* h = (uint32_t*)(ws + OFF_H);

  prep_w<<<NS1*4, 256, 0, stream>>>(W1, K1ACT, NS1, W1p);
  prep_w<<<NS2*4, 256, 0, stream>>>(W2, HID, NS2, W2p);
  prep_w<<<NS2*4, 256, 0, stream>>>(W3, HID, NS2, W3p);

  dim3 grid(NBLK), block(512);
  gemm_layer<0><<<grid, block, 0, stream>>>(xi, nullptr, W1p, b1, h,
                                            nullptr, nullptr, nullptr, NS1);
  gemm_layer<1><<<grid, block, 0, stream>>>(nullptr, h, W2p, b2, h,
                                            nullptr, nullptr, nullptr, NS2);
  gemm_layer<2><<<grid, block, 0, stream>>>(nullptr, h, W3p, b3, nullptr,
                                            W4, b4, out, NS2);
}

// Round 5
// 1254.123 us; speedup vs baseline: 1.0131x; 1.0131x over previous
//
#include <hip/hip_runtime.h>
#include <math.h>
#include <stdint.h>

typedef _Float16 f16;
typedef _Float16 f16x8 __attribute__((ext_vector_type(8)));
typedef float f32x4 __attribute__((ext_vector_type(4)));
typedef unsigned short u16;
typedef u16 u16x8 __attribute__((ext_vector_type(8)));

#define HID 256
#define K1ACT 3202
#define NS1 101               // ceil(3202/32), padded K = 3232
#define NS2 8                 // 256/32
#define NPX 65536
#define BPX 64
#define NBLK (NPX/BPX)        // 1024

// ws layout (bytes)
#define OFF_W1 0
#define SZ_W1  ((size_t)NS1*32768)
#define OFF_W2 SZ_W1
#define SZ_W2  ((size_t)NS2*32768)
#define OFF_W3 (OFF_W2+SZ_W2)
#define OFF_H  ((size_t)4194304)
// total = 4 MB + 65536*256*4 = 71,303,168 B

__device__ inline void split2(float v, u16& h, u16& l){
  f16 hv = (f16)v;
  f16 lv = (f16)(v - (float)hv);
  h = __builtin_bit_cast(u16, hv);
  l = __builtin_bit_cast(u16, lv);
}

// Pre-split W (fp32 [K][256]) into fp16 hi/lo MFMA-fragment units (proven r2 layout):
//   unit(s, w, nf, split, lane): 8 f16, j -> W[s*32 + (lane>>4)*8 + j][w*64 + nf*16 + (lane&15)]
//   unit offset = (((s*4 + w)*4 + nf)*2 + split)*64 + lane
__global__ void prep_w(const float* __restrict__ W, int Kact, int nStages,
                       u16* __restrict__ outp){
  int t = blockIdx.x*256 + threadIdx.x;
  if (t >= nStages*1024) return;
  int s = t >> 10, r = t & 1023;
  int w = r >> 8, nf = (r >> 6) & 3, l = r & 63;
  int col = w*64 + nf*16 + (l & 15);
  int kb  = s*32 + (l >> 4)*8;
  u16x8 hv, lv;
  #pragma unroll
  for (int j = 0; j < 8; ++j){
    int k = kb + j;
    float v = (k < Kact) ? W[(size_t)k*HID + col] : 0.f;
    u16 h, lo; split2(v, h, lo);
    hv[j] = h; lv[j] = lo;
  }
  size_t U0 = ((((size_t)s*4 + w)*4 + nf)*2 + 0)*64 + l;
  *(u16x8*)(outp + U0*8)      = hv;
  *(u16x8*)(outp + (U0+64)*8) = lv;
}

// ---------------------------------------------------------------------------
// 64px x 256col block, 4 waves (wave = 64px x 64col), double-buffered,
// one barrier per K-step, 80 KB LDS -> 2 independent blocks/CU.
// Full split-3 numerics in EVERY layer (round-2-proven):
//   A = hi/lo, B = hi/lo, acc += Ah*Bh + Al*Bh + Ah*Bl.
// Activations stored packed (hi | lo<<16) u32.
// MODE 0: A = im2col(xi)+coords. MODE 1: A = h. MODE 2: A = h + layer-4 tail.
// ---------------------------------------------------------------------------
template<int MODE>
__global__ __launch_bounds__(256, 2)
void gemm_layer(const float* __restrict__ xi, const uint32_t* __restrict__ hin,
                const u16* __restrict__ Wp, const float* __restrict__ bias,
                uint32_t* __restrict__ hout, const float* __restrict__ W4,
                const float* __restrict__ b4, float* __restrict__ out, int nt)
{
  constexpr bool L1 = (MODE == 0);
  __shared__ __align__(16) u16 Ab[2][4096];   // 8 KB per buf: (mf*2+split)*64+l units
  __shared__ __align__(16) u16 Bb[2][16384];  // 32 KB per buf

  const int tid  = threadIdx.x;
  const int lane = tid & 63;
  const int wv   = tid >> 6;          // wave id = col-group (uniform)

  int bid = blockIdx.x;
  bid = (bid & 7)*(NBLK/8) + (bid >> 3);   // XCD-chunked swizzle (1024%8==0)
  const int pxb = bid * BPX;
  const int y   = pxb >> 8;
  const int x0  = pxb & 255;

  const float gy  = -1.f + (2.f/255.f)*(float)y;
  const float gxA = -1.f + (2.f/255.f)*(float)(x0 + lane);

  f32x4 acc[4][4];
  #pragma unroll
  for (int a=0;a<4;a++)
    #pragma unroll
    for (int b=0;b<4;b++) acc[a][b] = f32x4{0.f,0.f,0.f,0.f};

  float    fa[8];     // MODE 0 prefetch regs (px = lane, k-octet = wv)
  uint32_t ua[8];     // MODE 1/2 prefetch regs (packed hi|lo)

#define A_LOAD(S) do { \
    if (L1){ \
      _Pragma("unroll") \
      for (int j=0;j<8;++j){ \
        int k = (S)*32 + wv*8 + j;              /* wave-uniform */ \
        float v = 0.f; \
        if (k < 3200){ \
          int c = k/25, rr = k - 25*c; \
          int dy = rr/5, dx = rr - dy*5; \
          int yy = y + dy - 2; \
          int xx = x0 + lane + dx - 2; \
          if ((unsigned)yy < 256u && (unsigned)xx < 256u) \
            v = xi[((size_t)c<<16) + ((size_t)yy<<8) + xx]; \
        } else if (k == 3200) v = gy; \
        else if (k == 3201) v = gxA; \
        fa[j] = v; \
      } \
    } else { \
      const uint32_t* hp = hin + (size_t)(pxb + lane)*HID + (S)*32 + wv*8; \
      uint4 a0 = *(const uint4*)hp; \
      uint4 a1 = *(const uint4*)(hp+4); \
      ua[0]=a0.x; ua[1]=a0.y; ua[2]=a0.z; ua[3]=a0.w; \
      ua[4]=a1.x; ua[5]=a1.y; ua[6]=a1.z; ua[7]=a1.w; \
    } \
  } while(0)

#define A_WRITE(BUF) do { \
    u16x8 hv, lv; \
    if (L1){ \
      _Pragma("unroll") \
      for (int j=0;j<8;++j){ u16 h,l; split2(fa[j],h,l); hv[j]=h; lv[j]=l; } \
    } else { \
      _Pragma("unroll") \
      for (int j=0;j<8;++j){ hv[j]=(u16)(ua[j]&0xffffu); lv[j]=(u16)(ua[j]>>16); } \
    } \
    int ub = ((lane>>4)*2)*64 + wv*16 + (lane&15); \
    *(u16x8*)(&Ab[BUF][(size_t)ub*8])      = hv; \
    *(u16x8*)(&Ab[BUF][(size_t)(ub+64)*8]) = lv; \
  } while(0)

#define B_STAGE(S, BUF) do { \
    const char* _src = (const char*)Wp + (size_t)(S)*32768 + wv*8192 + lane*16; \
    char* _dst = (char*)&Bb[BUF][0] + wv*8192; \
    _Pragma("unroll") \
    for (int i=0;i<8;++i) \
      __builtin_amdgcn_global_load_lds( \
        (const __attribute__((address_space(1))) uint32_t*)(_src + i*1024), \
        (__attribute__((address_space(3))) uint32_t*)(_dst + i*1024), 16, 0, 0); \
  } while(0)

  // prologue
  A_LOAD(0);
  B_STAGE(0, 0);
  A_WRITE(0);
  __syncthreads();

  int cur = 0;
  for (int t = 0; t < nt; ++t){
    const int nxt = cur ^ 1;
    if (t+1 < nt){
      A_LOAD(t+1);            // global -> regs, hides under MFMA
      B_STAGE(t+1, nxt);      // global -> LDS, drained by next barrier
    }
    // ---- compute step t from buf[cur] ----
    f16x8 ahf[4], alf[4];
    #pragma unroll
    for (int mf=0;mf<4;++mf){
      ahf[mf] = *(const f16x8*)(&Ab[cur][((size_t)((mf*2+0)*64 + lane))*8]);
      alf[mf] = *(const f16x8*)(&Ab[cur][((size_t)((mf*2+1)*64 + lane))*8]);
    }
    __builtin_amdgcn_s_setprio(1);
    #pragma unroll
    for (int nf=0;nf<4;++nf){
      f16x8 bh = *(const f16x8*)(&Bb[cur][((size_t)(((wv*4+nf)*2+0)*64 + lane))*8]);
      f16x8 bl = *(const f16x8*)(&Bb[cur][((size_t)(((wv*4+nf)*2+1)*64 + lane))*8]);
      #pragma unroll
      for (int mf=0;mf<4;++mf){
        acc[mf][nf] = __builtin_amdgcn_mfma_f32_16x16x32_f16(ahf[mf], bh, acc[mf][nf], 0,0,0);
        acc[mf][nf] = __builtin_amdgcn_mfma_f32_16x16x32_f16(alf[mf], bh, acc[mf][nf], 0,0,0);
        acc[mf][nf] = __builtin_amdgcn_mfma_f32_16x16x32_f16(ahf[mf], bl, acc[mf][nf], 0,0,0);
      }
    }
    __builtin_amdgcn_s_setprio(0);
    if (t+1 < nt) A_WRITE(nxt);
    __syncthreads();
    cur = nxt;
  }

  float bcol[4];
  #pragma unroll
  for (int nf=0;nf<4;++nf) bcol[nf] = bias[wv*64 + nf*16 + (lane&15)];

  if (MODE != 2){
    // h = sin(30 z) -> packed hi|lo u32, [px][ch]
    #pragma unroll
    for (int mf=0;mf<4;++mf)
      #pragma unroll
      for (int nf=0;nf<4;++nf)
        #pragma unroll
        for (int j=0;j<4;++j){
          float z = acc[mf][nf][j] + bcol[nf];
          float h = sinf(30.f*z);
          u16 hh,ll; split2(h,hh,ll);
          int row = mf*16 + (lane>>4)*4 + j;
          int col = wv*64 + nf*16 + (lane&15);
          hout[(size_t)(pxb+row)*HID + col] = (uint32_t)hh | ((uint32_t)ll<<16);
        }
  } else {
    float (*red)[64][3] = (float(*)[64][3])(void*)&Ab[0][0];  // 3 KB overlay, buffers dead
    float w4v[4][3];
    #pragma unroll
    for (int nf=0;nf<4;++nf){
      int col = wv*64 + nf*16 + (lane&15);
      w4v[nf][0]=W4[col*3+0]; w4v[nf][1]=W4[col*3+1]; w4v[nf][2]=W4[col*3+2];
    }
    #pragma unroll
    for (int mf=0;mf<4;++mf)
      #pragma unroll
      for (int j=0;j<4;++j){
        float s0=0.f,s1=0.f,s2=0.f;
        #pragma unroll
        for (int nf=0;nf<4;++nf){
          float h = sinf(30.f*(acc[mf][nf][j] + bcol[nf]));
          s0 += h*w4v[nf][0]; s1 += h*w4v[nf][1]; s2 += h*w4v[nf][2];
        }
        #pragma unroll
        for (int m=1;m<16;m<<=1){
          s0 += __shfl_xor(s0, m);
          s1 += __shfl_xor(s1, m);
          s2 += __shfl_xor(s2, m);
        }
        if ((lane & 15) == 0){
          int row = mf*16 + (lane>>4)*4 + j;
          red[wv][row][0]=s0; red[wv][row][1]=s1; red[wv][row][2]=s2;
        }
      }
    __syncthreads();
    if (tid < 192){
      int px = tid & 63, c = tid >> 6;
      float v = red[0][px][c]+red[1][px][c]+red[2][px][c]+red[3][px][c] + b4[c];
      out[(size_t)c*NPX + pxb + px] = v;
    }
  }
#undef A_LOAD
#undef A_WRITE
#undef B_STAGE
}

// ---------------------------------------------------------------------------
extern "C" void kernel_launch(void* const* d_in, const int* in_sizes, int n_in,
                              void* d_out, int out_size, void* d_ws, size_t ws_size,
                              hipStream_t stream) {
  const float* xi = (const float*)d_in[0];
  const float* W1 = (const float*)d_in[1];
  const float* b1 = (const float*)d_in[2];
  const float* W2 = (const float*)d_in[3];
  const float* b2 = (const float*)d_in[4];
  const float* W3 = (const float*)d_in[5];
  const float* b3 = (const float*)d_in[6];
  const float* W4 = (const float*)d_in[7];
  const float* b4 = (const float*)d_in[8];
  float* out = (float*)d_out;

  char* ws = (char*)d_ws;
  u16* W1p = (u16*)(ws + OFF_W1);
  u16* W2p = (u16*)(ws + OFF_W2);
  u16* W3p = (u16*)(ws + OFF_W3);
  uint32_t* h = (uint32_t*)(ws + OFF_H);

  prep_w<<<NS1*4, 256, 0, stream>>>(W1, K1ACT, NS1, W1p);
  prep_w<<<NS2*4, 256, 0, stream>>>(W2, HID, NS2, W2p);
  prep_w<<<NS2*4, 256, 0, stream>>>(W3, HID, NS2, W3p);

  dim3 grid(NBLK), block(256);
  gemm_layer<0><<<grid, block, 0, stream>>>(xi, nullptr, W1p, b1, h,
                                            nullptr, nullptr, nullptr, NS1);
  gemm_layer<1><<<grid, block, 0, stream>>>(nullptr, h, W2p, b2, h,
                                            nullptr, nullptr, nullptr, NS2);
  gemm_layer<2><<<grid, block, 0, stream>>>(nullptr, h, W3p, b3, nullptr,
                                            W4, b4, out, NS2);
}

// Round 7
// 1209.767 us; speedup vs baseline: 1.0503x; 1.0367x over previous
//
#include <hip/hip_runtime.h>
#include <math.h>
#include <stdint.h>

typedef _Float16 f16;
typedef _Float16 f16x8 __attribute__((ext_vector_type(8)));
typedef float f32x4 __attribute__((ext_vector_type(4)));
typedef unsigned short u16;
typedef u16 u16x8 __attribute__((ext_vector_type(8)));

#define HID 256
#define K1ACT 3202
#define NS1 101               // ceil(3202/32), padded K = 3232
#define NS2 8                 // 256/32
#define NPX 65536
#define BPX 64
#define NBLK (NPX/BPX)        // 1024 (layers 2/3)

// ws layout (bytes)
#define OFF_W1 0
#define SZ_W1  ((size_t)NS1*32768)
#define OFF_W2 SZ_W1
#define SZ_W2  ((size_t)NS2*32768)
#define OFF_W3 (OFF_W2+SZ_W2)
#define OFF_H  ((size_t)4194304)

__device__ inline void split2(float v, u16& h, u16& l){
  f16 hv = (f16)v;
  f16 lv = (f16)(v - (float)hv);
  h = __builtin_bit_cast(u16, hv);
  l = __builtin_bit_cast(u16, lv);
}

// Pre-split W (fp32 [K][256]) into fp16 hi/lo MFMA-fragment units (proven r2 layout):
//   unit(s, w, nf, split, lane): 8 f16, j -> W[s*32 + (lane>>4)*8 + j][w*64 + nf*16 + (lane&15)]
//   unit offset = (((s*4 + w)*4 + nf)*2 + split)*64 + lane ; per-s slab = 32 KB contiguous
__global__ void prep_w(const float* __restrict__ W, int Kact, int nStages,
                       u16* __restrict__ outp){
  int t = blockIdx.x*256 + threadIdx.x;
  if (t >= nStages*1024) return;
  int s = t >> 10, r = t & 1023;
  int w = r >> 8, nf = (r >> 6) & 3, l = r & 63;
  int col = w*64 + nf*16 + (l & 15);
  int kb  = s*32 + (l >> 4)*8;
  u16x8 hv, lv;
  #pragma unroll
  for (int j = 0; j < 8; ++j){
    int k = kb + j;
    float v = (k < Kact) ? W[(size_t)k*HID + col] : 0.f;
    u16 h, lo; split2(v, h, lo);
    hv[j] = h; lv[j] = lo;
  }
  size_t U0 = ((((size_t)s*4 + w)*4 + nf)*2 + 0)*64 + l;
  *(u16x8*)(outp + U0*8)      = hv;
  *(u16x8*)(outp + (U0+64)*8) = lv;
}

// ---------------------------------------------------------------------------
// Layer-1: 256px (one image row) x 256col per block, 512 thr = 8 waves,
// wave = 128px x 64col (96 MFMA/step). 1 block/CU (grid=256).
// Depth-2 A pipeline: A(t+1) loaded during step t-1, ds_written at TOP of
// step t (no mid-step vmcnt wait). B via global_load_lds issued at top.
// LDS: Ab 2 x 32 KB (16 mfb x 2 split x 64 units x 16 B)  [r6 bug: was 16 KB]
//      Bb 2 x 32 KB  -> 128 KB total, 1 block/CU.
// ---------------------------------------------------------------------------
__global__ __launch_bounds__(512, 2)
void gemm_l1(const float* __restrict__ xi, const u16* __restrict__ Wp,
             const float* __restrict__ bias, uint32_t* __restrict__ hout, int nt)
{
  __shared__ __align__(16) u16 Ab[2][16384];   // 32 KB/buf: [mfb(16)][split(2)][unit(64)][8]
  __shared__ __align__(16) u16 Bb[2][16384];   // 32 KB/buf: [(wn*4+nf)(16)][split(2)][unit(64)][8]

  const int tid  = threadIdx.x;
  const int lane = tid & 63;
  const int wv   = tid >> 6;              // 0..7
  const int wm   = wv >> 2, wn = wv & 3;  // wave = px-half wm, col-quarter wn
  const int y    = blockIdx.x;            // one image row per block
  const int oct  = wv >> 1;               // wave-uniform k-octet 0..3
  const int pxv  = (wv & 1)*64 + lane;    // 0..127 (this thread covers pxv, pxv+128)

  const float gy  = -1.f + (2.f/255.f)*(float)y;
  const float gx0 = -1.f + (2.f/255.f)*(float)pxv;
  const float gx1 = -1.f + (2.f/255.f)*(float)(pxv + 128);

  float fa[16];
  f32x4 acc[8][4];
  #pragma unroll
  for (int a=0;a<8;a++)
    #pragma unroll
    for (int b=0;b<4;b++) acc[a][b] = f32x4{0.f,0.f,0.f,0.f};

#define L1_ALOAD(S) do{ \
  _Pragma("unroll") \
  for (int j=0;j<8;++j){ \
    int k = (S)*32 + oct*8 + j; \
    float v0=0.f, v1=0.f; \
    if (k < 3200){ \
      int c = k/25, rr = k - 25*c;        /* uniform (SALU) */ \
      int dy = rr/5, dx = rr - dy*5; \
      int yy = y + dy - 2; \
      if ((unsigned)yy < 256u){ \
        const float* _row = xi + ((size_t)c<<16) + ((size_t)yy<<8); \
        int xx0 = pxv + dx - 2; \
        int xx1 = xx0 + 128; \
        if ((unsigned)xx0 < 256u) v0 = _row[xx0]; \
        if ((unsigned)xx1 < 256u) v1 = _row[xx1]; \
      } \
    } else if (k == 3200){ v0 = gy;  v1 = gy;  } \
    else if (k == 3201){ v0 = gx0; v1 = gx1; } \
    fa[j] = v0; fa[8+j] = v1; \
  }}while(0)

#define L1_AWRITE(BUF) do{ \
  _Pragma("unroll") \
  for (int hf=0; hf<2; ++hf){ \
    u16x8 hv, lv; \
    _Pragma("unroll") \
    for (int j=0;j<8;++j){ u16 h,l; split2(fa[hf*8+j],h,l); hv[j]=h; lv[j]=l; } \
    int mfb = hf*8 + (wv&1)*4 + (lane>>4);     /* = (pxv+hf*128)>>4 */ \
    int e   = (oct*16 + (lane&15))*8; \
    *(u16x8*)(&Ab[BUF][(size_t)(mfb*2+0)*512 + e]) = hv; \
    *(u16x8*)(&Ab[BUF][(size_t)(mfb*2+1)*512 + e]) = lv; \
  }}while(0)

#define L1_BSTAGE(S,BUF) do{ \
  const char* _s = (const char*)Wp + (size_t)(S)*32768 + tid*16; \
  char* _d = (char*)&Bb[BUF][0] + tid*16; \
  _Pragma("unroll") \
  for (int i=0;i<4;++i) \
    __builtin_amdgcn_global_load_lds( \
      (const __attribute__((address_space(1))) uint32_t*)(_s + i*8192), \
      (__attribute__((address_space(3))) uint32_t*)(_d + i*8192), 16, 0, 0); \
 }while(0)

  // prologue: stage s=0, prefetch s=1 into regs
  L1_ALOAD(0);
  L1_AWRITE(0);
  L1_ALOAD(1);
  L1_BSTAGE(0, 0);
  __syncthreads();

  int cur = 0;
  for (int t = 0; t < nt; ++t){
    const int nxt = cur ^ 1;
    if (t+1 < nt){
      L1_AWRITE(nxt);        // fa holds s=t+1 (loaded last step; drained by barrier) — no wait
      L1_BSTAGE(t+1, nxt);   // issued at top; ~full step of cover before barrier drain
    }
    if (t+2 < nt) L1_ALOAD(t+2);   // refill fa after AWRITE consumed it

    // B fragments are hf-invariant: load once per step (8 ds_read_b128)
    f16x8 bh[4], bl[4];
    #pragma unroll
    for (int nf=0;nf<4;++nf){
      bh[nf] = *(const f16x8*)(&Bb[cur][(size_t)((wn*4+nf)*2+0)*512 + lane*8]);
      bl[nf] = *(const f16x8*)(&Bb[cur][(size_t)((wn*4+nf)*2+1)*512 + lane*8]);
    }
    __builtin_amdgcn_s_setprio(1);
    #pragma unroll
    for (int hf=0; hf<2; ++hf){
      f16x8 ah[4], al[4];
      #pragma unroll
      for (int m2=0;m2<4;++m2){
        int mfb = wm*8 + hf*4 + m2;
        ah[m2] = *(const f16x8*)(&Ab[cur][(size_t)(mfb*2+0)*512 + lane*8]);
        al[m2] = *(const f16x8*)(&Ab[cur][(size_t)(mfb*2+1)*512 + lane*8]);
      }
      #pragma unroll
      for (int nf=0;nf<4;++nf){
        #pragma unroll
        for (int m2=0;m2<4;++m2){
          acc[hf*4+m2][nf] = __builtin_amdgcn_mfma_f32_16x16x32_f16(ah[m2], bh[nf], acc[hf*4+m2][nf], 0,0,0);
          acc[hf*4+m2][nf] = __builtin_amdgcn_mfma_f32_16x16x32_f16(al[m2], bh[nf], acc[hf*4+m2][nf], 0,0,0);
          acc[hf*4+m2][nf] = __builtin_amdgcn_mfma_f32_16x16x32_f16(ah[m2], bl[nf], acc[hf*4+m2][nf], 0,0,0);
        }
      }
    }
    __builtin_amdgcn_s_setprio(0);
    __syncthreads();
    cur = nxt;
  }

  // epilogue: h = sin(30 z) -> packed hi|lo u32, [px][ch]
  float bcol[4];
  #pragma unroll
  for (int nf=0;nf<4;++nf) bcol[nf] = bias[wn*64 + nf*16 + (lane&15)];
  #pragma unroll
  for (int mf=0;mf<8;++mf)
    #pragma unroll
    for (int nf=0;nf<4;++nf)
      #pragma unroll
      for (int j=0;j<4;++j){
        float z = acc[mf][nf][j] + bcol[nf];
        float h = sinf(30.f*z);
        u16 hh,ll; split2(h,hh,ll);
        int row = (wm*8 + mf)*16 + (lane>>4)*4 + j;   // 0..255 within this image row
        int col = wn*64 + nf*16 + (lane&15);
        hout[((size_t)y*256 + row)*HID + col] = (uint32_t)hh | ((uint32_t)ll<<16);
      }
#undef L1_ALOAD
#undef L1_AWRITE
#undef L1_BSTAGE
}

// ---------------------------------------------------------------------------
// Layers 2/3(+4 tail): unchanged r5 structure (64px x 256col, 4 waves, dbuf).
// MODE 1: A = h; MODE 2: A = h + fused layer-4 tail.
// ---------------------------------------------------------------------------
template<int MODE>
__global__ __launch_bounds__(256, 2)
void gemm_layer(const uint32_t* __restrict__ hin,
                const u16* __restrict__ Wp, const float* __restrict__ bias,
                uint32_t* __restrict__ hout, const float* __restrict__ W4,
                const float* __restrict__ b4, float* __restrict__ out, int nt)
{
  __shared__ __align__(16) u16 Ab[2][4096];   // 8 KB per buf
  __shared__ __align__(16) u16 Bb[2][16384];  // 32 KB per buf

  const int tid  = threadIdx.x;
  const int lane = tid & 63;
  const int wv   = tid >> 6;

  int bid = blockIdx.x;
  bid = (bid & 7)*(NBLK/8) + (bid >> 3);   // XCD-chunked swizzle (1024%8==0)
  const int pxb = bid * BPX;

  f32x4 acc[4][4];
  #pragma unroll
  for (int a=0;a<4;a++)
    #pragma unroll
    for (int b=0;b<4;b++) acc[a][b] = f32x4{0.f,0.f,0.f,0.f};

  uint32_t ua[8];

#define A_LOAD(S) do { \
    const uint32_t* hp = hin + (size_t)(pxb + lane)*HID + (S)*32 + wv*8; \
    uint4 a0 = *(const uint4*)hp; \
    uint4 a1 = *(const uint4*)(hp+4); \
    ua[0]=a0.x; ua[1]=a0.y; ua[2]=a0.z; ua[3]=a0.w; \
    ua[4]=a1.x; ua[5]=a1.y; ua[6]=a1.z; ua[7]=a1.w; \
  } while(0)

#define A_WRITE(BUF) do { \
    u16x8 hv, lv; \
    _Pragma("unroll") \
    for (int j=0;j<8;++j){ hv[j]=(u16)(ua[j]&0xffffu); lv[j]=(u16)(ua[j]>>16); } \
    int ub = ((lane>>4)*2)*64 + wv*16 + (lane&15); \
    *(u16x8*)(&Ab[BUF][(size_t)ub*8])      = hv; \
    *(u16x8*)(&Ab[BUF][(size_t)(ub+64)*8]) = lv; \
  } while(0)

#define B_STAGE(S, BUF) do { \
    const char* _src = (const char*)Wp + (size_t)(S)*32768 + wv*8192 + lane*16; \
    char* _dst = (char*)&Bb[BUF][0] + wv*8192; \
    _Pragma("unroll") \
    for (int i=0;i<8;++i) \
      __builtin_amdgcn_global_load_lds( \
        (const __attribute__((address_space(1))) uint32_t*)(_src + i*1024), \
        (__attribute__((address_space(3))) uint32_t*)(_dst + i*1024), 16, 0, 0); \
  } while(0)

  A_LOAD(0);
  B_STAGE(0, 0);
  A_WRITE(0);
  __syncthreads();

  int cur = 0;
  for (int t = 0; t < nt; ++t){
    const int nxt = cur ^ 1;
    if (t+1 < nt){
      A_LOAD(t+1);
      B_STAGE(t+1, nxt);
    }
    f16x8 ahf[4], alf[4];
    #pragma unroll
    for (int mf=0;mf<4;++mf){
      ahf[mf] = *(const f16x8*)(&Ab[cur][((size_t)((mf*2+0)*64 + lane))*8]);
      alf[mf] = *(const f16x8*)(&Ab[cur][((size_t)((mf*2+1)*64 + lane))*8]);
    }
    __builtin_amdgcn_s_setprio(1);
    #pragma unroll
    for (int nf=0;nf<4;++nf){
      f16x8 bh = *(const f16x8*)(&Bb[cur][((size_t)(((wv*4+nf)*2+0)*64 + lane))*8]);
      f16x8 bl = *(const f16x8*)(&Bb[cur][((size_t)(((wv*4+nf)*2+1)*64 + lane))*8]);
      #pragma unroll
      for (int mf=0;mf<4;++mf){
        acc[mf][nf] = __builtin_amdgcn_mfma_f32_16x16x32_f16(ahf[mf], bh, acc[mf][nf], 0,0,0);
        acc[mf][nf] = __builtin_amdgcn_mfma_f32_16x16x32_f16(alf[mf], bh, acc[mf][nf], 0,0,0);
        acc[mf][nf] = __builtin_amdgcn_mfma_f32_16x16x32_f16(ahf[mf], bl, acc[mf][nf], 0,0,0);
      }
    }
    __builtin_amdgcn_s_setprio(0);
    if (t+1 < nt) A_WRITE(nxt);
    __syncthreads();
    cur = nxt;
  }

  float bcol[4];
  #pragma unroll
  for (int nf=0;nf<4;++nf) bcol[nf] = bias[wv*64 + nf*16 + (lane&15)];

  if (MODE != 2){
    #pragma unroll
    for (int mf=0;mf<4;++mf)
      #pragma unroll
      for (int nf=0;nf<4;++nf)
        #pragma unroll
        for (int j=0;j<4;++j){
          float z = acc[mf][nf][j] + bcol[nf];
          float h = sinf(30.f*z);
          u16 hh,ll; split2(h,hh,ll);
          int row = mf*16 + (lane>>4)*4 + j;
          int col = wv*64 + nf*16 + (lane&15);
          hout[(size_t)(pxb+row)*HID + col] = (uint32_t)hh | ((uint32_t)ll<<16);
        }
  } else {
    float (*red)[64][3] = (float(*)[64][3])(void*)&Ab[0][0];
    float w4v[4][3];
    #pragma unroll
    for (int nf=0;nf<4;++nf){
      int col = wv*64 + nf*16 + (lane&15);
      w4v[nf][0]=W4[col*3+0]; w4v[nf][1]=W4[col*3+1]; w4v[nf][2]=W4[col*3+2];
    }
    #pragma unroll
    for (int mf=0;mf<4;++mf)
      #pragma unroll
      for (int j=0;j<4;++j){
        float s0=0.f,s1=0.f,s2=0.f;
        #pragma unroll
        for (int nf=0;nf<4;++nf){
          float h = sinf(30.f*(acc[mf][nf][j] + bcol[nf]));
          s0 += h*w4v[nf][0]; s1 += h*w4v[nf][1]; s2 += h*w4v[nf][2];
        }
        #pragma unroll
        for (int m=1;m<16;m<<=1){
          s0 += __shfl_xor(s0, m);
          s1 += __shfl_xor(s1, m);
          s2 += __shfl_xor(s2, m);
        }
        if ((lane & 15) == 0){
          int row = mf*16 + (lane>>4)*4 + j;
          red[wv][row][0]=s0; red[wv][row][1]=s1; red[wv][row][2]=s2;
        }
      }
    __syncthreads();
    if (tid < 192){
      int px = tid & 63, c = tid >> 6;
      float v = red[0][px][c]+red[1][px][c]+red[2][px][c]+red[3][px][c] + b4[c];
      out[(size_t)c*NPX + pxb + px] = v;
    }
  }
#undef A_LOAD
#undef A_WRITE
#undef B_STAGE
}

// ---------------------------------------------------------------------------
extern "C" void kernel_launch(void* const* d_in, const int* in_sizes, int n_in,
                              void* d_out, int out_size, void* d_ws, size_t ws_size,
                              hipStream_t stream) {
  const float* xi = (const float*)d_in[0];
  const float* W1 = (const float*)d_in[1];
  const float* b1 = (const float*)d_in[2];
  const float* W2 = (const float*)d_in[3];
  const float* b2 = (const float*)d_in[4];
  const float* W3 = (const float*)d_in[5];
  const float* b3 = (const float*)d_in[6];
  const float* W4 = (const float*)d_in[7];
  const float* b4 = (const float*)d_in[8];
  float* out = (float*)d_out;

  char* ws = (char*)d_ws;
  u16* W1p = (u16*)(ws + OFF_W1);
  u16* W2p = (u16*)(ws + OFF_W2);
  u16* W3p = (u16*)(ws + OFF_W3);
  uint32_t* h = (uint32_t*)(ws + OFF_H);

  prep_w<<<NS1*4, 256, 0, stream>>>(W1, K1ACT, NS1, W1p);
  prep_w<<<NS2*4, 256, 0, stream>>>(W2, HID, NS2, W2p);
  prep_w<<<NS2*4, 256, 0, stream>>>(W3, HID, NS2, W3p);

  gemm_l1<<<256, 512, 0, stream>>>(xi, W1p, b1, h, NS1);

  dim3 grid(NBLK), block(256);
  gemm_layer<1><<<grid, block, 0, stream>>>(h, W2p, b2, h,
                                            nullptr, nullptr, nullptr, NS2);
  gemm_layer<2><<<grid, block, 0, stream>>>(h, W3p, b3, nullptr,
                                            W4, b4, out, NS2);
}